// Round 2
// baseline (142.314 us; speedup 1.0000x reference)
//
#include <hip/hip_runtime.h>

// The reference, as literally written, is degenerate:
//   k/v carry a singleton head axis; einsum('bhqd,bskd->bhqk') sums away the
//   key-position axis 's' and leaves a size-1 'k' axis; jnp.where broadcasts
//   it across the causal mask, so every softmax row is constant -> exactly
//   uniform weights. Q, K, RoPE, and causality all cancel. The result is
//     out[b,t,n] = sum_d V_sum[b,d] * (sum_h Wo[64h+d, n]) + bo[n]
//   with V_sum[b,:] = (sum_t x[b,t,:]) @ Wv + T*bv  -- constant over t.
// Evidence: ref absmax ~52.5 matches this computation's magnitude (std ~13),
// while true attention output would be ~0.3. We replicate the degenerate math.

namespace {
constexpr int B  = 8;
constexpr int T  = 1000;
constexpr int D  = 1024;
constexpr int HD = 64;
}

// ---------------------------------------------------------------------------
// K1: xs[b][c] = sum_t x[b,t,c]   (atomicAdd over 32 t-segments per batch)
// ---------------------------------------------------------------------------
__global__ __launch_bounds__(256)
void xsum_kernel(const float* __restrict__ x, float* __restrict__ xs)
{
    const int seg = blockIdx.x;            // 0..31
    const int b   = blockIdx.y;            // 0..7
    const int t0  = seg * 32;
    const int tn  = min(32, T - t0);
    const int c4  = threadIdx.x * 4;       // 0..1020
    float4 acc = make_float4(0.f, 0.f, 0.f, 0.f);
    const float* base = x + ((size_t)b * T + t0) * D + c4;
    for (int i = 0; i < tn; ++i) {
        const float4 v = *(const float4*)(base + (size_t)i * D);
        acc.x += v.x; acc.y += v.y; acc.z += v.z; acc.w += v.w;
    }
    float* dst = xs + b * D + c4;
    atomicAdd(dst + 0, acc.x);
    atomicAdd(dst + 1, acc.y);
    atomicAdd(dst + 2, acc.z);
    atomicAdd(dst + 3, acc.w);
}

// ---------------------------------------------------------------------------
// K2: vs[b][d] = xs[b,:] . Wv[:,d] + T*bv[d]    (one block per b)
// ---------------------------------------------------------------------------
__global__ __launch_bounds__(256)
void vsum_kernel(const float* __restrict__ xs, const float* __restrict__ Wv,
                 const float* __restrict__ bv, float* __restrict__ vs)
{
    __shared__ float part[4][HD];
    const int b  = blockIdx.x;
    const int d  = threadIdx.x & 63;
    const int sl = threadIdx.x >> 6;       // 0..3 (one wave per slice)
    const int k0 = sl * 256;
    float acc = 0.f;
    for (int k = 0; k < 256; ++k)
        acc = fmaf(xs[b * D + k0 + k], Wv[(size_t)(k0 + k) * HD + d], acc);
    part[sl][d] = acc;
    __syncthreads();
    if (threadIdx.x < HD) {
        const int dd = threadIdx.x;
        vs[b * HD + dd] = part[0][dd] + part[1][dd] + part[2][dd] + part[3][dd]
                        + (float)T * bv[dd];
    }
}

// ---------------------------------------------------------------------------
// K3: ro[b][n] += sum_{k in chunk} vs[b, k&63] * Wo[k, n]
//     grid (4 n-chunks of 256, 8 k-chunks of 128); bo added in K4.
// ---------------------------------------------------------------------------
__global__ __launch_bounds__(256)
void rowout_kernel(const float* __restrict__ vs, const float* __restrict__ Wo,
                   float* __restrict__ ro)
{
    __shared__ float vsl[B * HD];          // all 512 V_sum values
    const int n  = blockIdx.x * 256 + threadIdx.x;
    const int k0 = blockIdx.y * 128;
    vsl[threadIdx.x]       = vs[threadIdx.x];
    vsl[threadIdx.x + 256] = vs[threadIdx.x + 256];
    __syncthreads();

    float acc[B];
    #pragma unroll
    for (int b = 0; b < B; ++b) acc[b] = 0.f;

    for (int kk = 0; kk < 128; ++kk) {
        const int k = k0 + kk;
        const float w = Wo[(size_t)k * D + n];   // coalesced across threads
        const int d = k & 63;                    // LDS broadcast (same addr)
        #pragma unroll
        for (int b = 0; b < B; ++b)
            acc[b] = fmaf(vsl[b * HD + d], w, acc[b]);
    }
    #pragma unroll
    for (int b = 0; b < B; ++b)
        atomicAdd(&ro[b * D + n], acc[b]);
}

// ---------------------------------------------------------------------------
// K4: out[b,t,:] = ro[b,:] + bo[:]   (one block per (t,b) row, float4 stores)
// ---------------------------------------------------------------------------
__global__ __launch_bounds__(256)
void bcast_kernel(const float* __restrict__ ro, const float* __restrict__ bo,
                  float* __restrict__ out)
{
    const int t  = blockIdx.x;             // 0..999
    const int b  = blockIdx.y;             // 0..7
    const int c4 = threadIdx.x * 4;
    float4 r = *(const float4*)(ro + b * D + c4);
    const float4 bb = *(const float4*)(bo + c4);
    r.x += bb.x; r.y += bb.y; r.z += bb.z; r.w += bb.w;
    *(float4*)(out + ((size_t)b * T + t) * D + c4) = r;
}

// ---------------------------------------------------------------------------
extern "C" void kernel_launch(void* const* d_in, const int* in_sizes, int n_in,
                              void* d_out, int out_size, void* d_ws, size_t ws_size,
                              hipStream_t stream)
{
    const float* x  = (const float*)d_in[0];
    const float* Wv = (const float*)d_in[5];
    const float* bv = (const float*)d_in[6];
    const float* Wo = (const float*)d_in[7];
    const float* bo = (const float*)d_in[8];
    float* out = (float*)d_out;

    // ws layout (floats): xs[8192] | vs[512] | ro[8192]
    float* xs = (float*)d_ws;
    float* vs = xs + B * D;
    float* ro = vs + B * HD;

    // zero the accumulators (ws is poisoned 0xAA before every launch)
    hipMemsetAsync(d_ws, 0, (size_t)(B * D + B * HD + B * D) * sizeof(float),
                   stream);

    xsum_kernel  <<<dim3(32, B), 256, 0, stream>>>(x, xs);
    vsum_kernel  <<<dim3(B),     256, 0, stream>>>(xs, Wv, bv, vs);
    rowout_kernel<<<dim3(4, 8),  256, 0, stream>>>(vs, Wo, ro);
    bcast_kernel <<<dim3(T, B),  256, 0, stream>>>(ro, bo, out);
}